// Round 5
// baseline (960.977 us; speedup 1.0000x reference)
//
#include <hip/hip_runtime.h>
#include <hip/hip_bf16.h>
#include <math.h>

// B=2, T=32, H=32, W=32, HID=64, IN=384, OUT=384, L=1024, rows=65536
// h5 layout: [b][c][t][l] -> b*2097152 + c*32768 + t*1024 + l
// OUTPUT IS FLOAT32 (reference returns fp32).
// ws layout (float offsets): gf[128] @0, bnp[256] @128, stat[256] @384,
// h5 @1024, a1 @4195328, a2 @8389632, x3(bf16) @12583936. total = 58.7 MB
// R10: k1 4x4 tile was LDS-pipe-throughput-bound (VALUBusy 34% == 128/384
// predicted duty). -> 8x4 tile, 128x64 block, same dbuf 1-barrier schedule,
// cap (256,2). History: R1 (256,4) spilled; R3 (256,1) VGPR=256 -> 1-2
// waves/SIMD latency-bound; R4 4x4 = 128us LDS-bound.
// Also: BN stats fused into k2c (atomicAdd partials, zeroed in k0);
// k2d is now a 1-block finalize (was a 67MB re-read).

#define OFF_GF 0
#define OFF_BN 128
#define OFF_ST 384
#define OFF_H5 1024
#define OFF_A1 4195328
#define OFF_A2 8389632
#define OFF_X3 12583936

__device__ __forceinline__ float gelu_f(float v) {
    return 0.5f * v * (1.0f + erff(v * 0.70710678118654752f));
}

// ---------------------------------------------------------------------------
// K0: g = ifft_T(fw), F = ifft_T(fb) (T=32). gf: gr[32] gi[32] Fr[32] Fi[32]
// Also zeroes the BN-stat accumulators (re-zeroed on every graph replay).
// ---------------------------------------------------------------------------
__global__ __launch_bounds__(64) void k0_prep(const float* __restrict__ fw,
                                              const float* __restrict__ fb,
                                              float* __restrict__ gf,
                                              float* __restrict__ stat) {
    int tid = threadIdx.x;
    stat[tid] = 0.f;
    stat[64 + tid] = 0.f;
    stat[128 + tid] = 0.f;
    stat[192 + tid] = 0.f;
    if (tid < 32) {
        float gr = 0.f, gi = 0.f, Fr = 0.f, Fi = 0.f;
        for (int f = 0; f < 32; f++) {
            int ph = (f * tid) & 31;
            float ang = 6.283185307179586f * (float)ph * (1.0f / 32.0f);
            float s, c;
            __sincosf(ang, &s, &c);
            float wv = fw[f], bv = fb[f];
            gr += wv * c; gi += wv * s;
            Fr += bv * c; Fi += bv * s;
        }
        const float inv = 1.0f / 32.0f;
        gf[tid]      = gr * inv;
        gf[32 + tid] = gi * inv;
        gf[64 + tid] = Fr * inv;
        gf[96 + tid] = Fi * inv;
    }
}

// ---------------------------------------------------------------------------
// K1: down GEMM + bias + GELU -> h5 (channel-planar).
// 512 blocks x 256 thr. Block: 128 rows x 64 ch, K=384 in 12 steps of 32.
// Thread: 8 rows x 4 ch (12 ds_read_b128 per 128 FMA4 -> 1.5x fewer LDS
// insts than 4x4). Double-buffered LDS, ONE barrier per K-step, loads
// issued 2 steps ahead. Epilogue: gelu+bias -> LDS transpose -> planar
// float4 h5 stores. VGPR budget ~119 under cap 128 (256,2).
// ---------------------------------------------------------------------------
__global__ __launch_bounds__(256, 2) void k1_down(const float* __restrict__ x,
                                                  const float* __restrict__ dw,
                                                  const float* __restrict__ db,
                                                  float* __restrict__ h5) {
    // buf k at sm + k*6912: xs[128*36] then ws[64*36]
    __shared__ __align__(16) float sm[13824];
    const int tid = threadIdx.x;
    const int row0 = blockIdx.x * 128;
    const int cg = tid & 15;   // ch  = cg + 16*i, i<4
    const int rg = tid >> 4;   // row = rg + 16*j, j<8   (rg 0..15)

    // staging coords: x rows sr+32k (k<4), w rows sr, sr+32; k-quad sk
    const int sr = tid >> 3;        // 0..31
    const int sk = (tid & 7) * 4;   // 0,4,...,28
    const float* xp = x + (row0 + sr) * 384 + sk;
    const float* wp = dw + sr * 384 + sk;

    float acc[8][4];
#pragma unroll
    for (int j = 0; j < 8; j++)
#pragma unroll
        for (int i = 0; i < 4; i++) acc[j][i] = 0.f;

    // prologue: tile 0 -> buf0, issue tile 1 loads
    float4 rx0 = *(const float4*)(xp);
    float4 rx1 = *(const float4*)(xp + 32 * 384);
    float4 rx2 = *(const float4*)(xp + 64 * 384);
    float4 rx3 = *(const float4*)(xp + 96 * 384);
    float4 rw0 = *(const float4*)(wp);
    float4 rw1 = *(const float4*)(wp + 32 * 384);
    *(float4*)(sm + (sr)      * 36 + sk) = rx0;
    *(float4*)(sm + (sr + 32) * 36 + sk) = rx1;
    *(float4*)(sm + (sr + 64) * 36 + sk) = rx2;
    *(float4*)(sm + (sr + 96) * 36 + sk) = rx3;
    *(float4*)(sm + 4608 + (sr)      * 36 + sk) = rw0;
    *(float4*)(sm + 4608 + (sr + 32) * 36 + sk) = rw1;
    rx0 = *(const float4*)(xp + 32);
    rx1 = *(const float4*)(xp + 32 + 32 * 384);
    rx2 = *(const float4*)(xp + 32 + 64 * 384);
    rx3 = *(const float4*)(xp + 32 + 96 * 384);
    rw0 = *(const float4*)(wp + 32);
    rw1 = *(const float4*)(wp + 32 + 32 * 384);
    __syncthreads();

    for (int s = 0; s < 12; s++) {
        float* cb = sm + (s & 1) * 6912;         // compute buffer
        float* nb = sm + ((s + 1) & 1) * 6912;   // next buffer
        if (s < 11) {
            // tile s+1 regs -> nb (vmcnt wait lands here); safe: nb's last
            // readers (tile s-1 compute) finished before the last barrier.
            *(float4*)(nb + (sr)      * 36 + sk) = rx0;
            *(float4*)(nb + (sr + 32) * 36 + sk) = rx1;
            *(float4*)(nb + (sr + 64) * 36 + sk) = rx2;
            *(float4*)(nb + (sr + 96) * 36 + sk) = rx3;
            *(float4*)(nb + 4608 + (sr)      * 36 + sk) = rw0;
            *(float4*)(nb + 4608 + (sr + 32) * 36 + sk) = rw1;
            if (s < 10) {
                const int kc = (s + 2) * 32;
                rx0 = *(const float4*)(xp + kc);
                rx1 = *(const float4*)(xp + kc + 32 * 384);
                rx2 = *(const float4*)(xp + kc + 64 * 384);
                rx3 = *(const float4*)(xp + kc + 96 * 384);
                rw0 = *(const float4*)(wp + kc);
                rw1 = *(const float4*)(wp + kc + 32 * 384);
            }
        }
#pragma unroll
        for (int kq = 0; kq < 8; kq++) {
            float4 wv[4], xv[8];
#pragma unroll
            for (int i = 0; i < 4; i++)   // stride 144B: 2-way alias (free)
                wv[i] = *(const float4*)(cb + 4608 + (cg + 16 * i) * 36 + kq * 4);
#pragma unroll
            for (int j = 0; j < 8; j++)   // 4 addrs/wave, 16-lane broadcast
                xv[j] = *(const float4*)(cb + (rg + 16 * j) * 36 + kq * 4);
#pragma unroll
            for (int j = 0; j < 8; j++)
#pragma unroll
                for (int i = 0; i < 4; i++)
                    acc[j][i] += xv[j].x * wv[i].x + xv[j].y * wv[i].y +
                                 xv[j].z * wv[i].z + xv[j].w * wv[i].w;
        }
        __syncthreads();
    }

    // epilogue: gelu(acc+bias) -> st[c][r] (stride 132) -> planar float4
    const int b = row0 >> 15;
    const int t = (row0 >> 10) & 31;
    const int l0 = row0 & 1023;
    float bz[4];
#pragma unroll
    for (int i = 0; i < 4; i++) bz[i] = db[cg + 16 * i];
    float* st = sm;   // 64*132 = 8448 <= 13824
#pragma unroll
    for (int j = 0; j < 8; j++)
#pragma unroll
        for (int i = 0; i < 4; i++)
            st[(cg + 16 * i) * 132 + (rg + 16 * j)] = gelu_f(acc[j][i] + bz[i]);
    __syncthreads();
    const int r4 = (tid & 31) * 4;   // 0..124
    const int cr = tid >> 5;         // 0..7
#pragma unroll
    for (int pass = 0; pass < 8; pass++) {
        const int c = cr + 8 * pass;
        float4 v = *(const float4*)(st + c * 132 + r4);
        *(float4*)(h5 + b * 2097152 + c * 32768 + t * 1024 + l0 + r4) = v;
    }
}

// ---------------------------------------------------------------------------
// K2a: spatial depthwise (1,3,3) pad1 & (1,5,5) pad2 per (b,c,t) plane.
// 4096 blocks x 256 thr.
// ---------------------------------------------------------------------------
__global__ __launch_bounds__(256) void k2a_spatial(const float* __restrict__ h5,
                                                   const float* __restrict__ k31w,
                                                   const float* __restrict__ k31b,
                                                   const float* __restrict__ k51w,
                                                   const float* __restrict__ k51b,
                                                   float* __restrict__ a1,
                                                   float* __restrict__ a2) {
    __shared__ float pl[32 * 33];
    __shared__ float w3[9];
    __shared__ float w5[25];
    const int tid = threadIdx.x;
    const int bct = blockIdx.x;
    const int base = bct << 10;
    const int c = (bct >> 5) & 63;

#pragma unroll
    for (int i = 0; i < 4; i++) {
        int l = tid + i * 256;
        pl[(l >> 5) * 33 + (l & 31)] = h5[base + l];
    }
    if (tid < 9)  w3[tid] = k31w[c * 9 + tid];
    if (tid < 25) w5[tid] = k51w[c * 25 + tid];
    float b3 = k31b[c], b5 = k51b[c];
    __syncthreads();

#pragma unroll
    for (int i = 0; i < 4; i++) {
        int l = tid + i * 256;
        int h = l >> 5, w = l & 31;
        float s3 = b3;
#pragma unroll
        for (int dh = -1; dh <= 1; dh++) {
            int hh = h + dh;
            if (hh < 0 || hh > 31) continue;
#pragma unroll
            for (int dwi = -1; dwi <= 1; dwi++) {
                int ww = w + dwi;
                if (ww < 0 || ww > 31) continue;
                s3 += pl[hh * 33 + ww] * w3[(dh + 1) * 3 + dwi + 1];
            }
        }
        float s5 = b5;
#pragma unroll
        for (int dh = -2; dh <= 2; dh++) {
            int hh = h + dh;
            if (hh < 0 || hh > 31) continue;
#pragma unroll
            for (int dwi = -2; dwi <= 2; dwi++) {
                int ww = w + dwi;
                if (ww < 0 || ww > 31) continue;
                s5 += pl[hh * 33 + ww] * w5[(dh + 2) * 5 + dwi + 2];
            }
        }
        a1[base + l] = s3;
        a2[base + l] = s5;
    }
}

// ---------------------------------------------------------------------------
// K2b: FFT branch = complex circular conv along T (+ ifft(fb) delta at l==0),
// magnitude -> x3 (bf16). 512 blocks x 256 thr.
// ---------------------------------------------------------------------------
__global__ __launch_bounds__(256) void k2b_fft(const float* __restrict__ h5,
                                               __hip_bfloat16* __restrict__ x3,
                                               const float* __restrict__ gf) {
    __shared__ float col[32 * 256];
    __shared__ float gfs[128];
    const int tid = threadIdx.x;
    const int bid = blockIdx.x;
    const int bc = bid >> 2;
    const int l = (bid & 3) * 256 + tid;
    const int base = bc * 32768 + l;

    if (tid < 128) gfs[tid] = gf[tid];
#pragma unroll
    for (int t = 0; t < 32; t++) col[t * 256 + tid] = h5[base + t * 1024];
    __syncthreads();

    const bool dc = (l == 0);
    for (int t = 0; t < 32; t++) {
        float ar = dc ? gfs[64 + t] : 0.f;
        float ai = dc ? gfs[96 + t] : 0.f;
#pragma unroll
        for (int d = 0; d < 32; d++) {
            float xv = col[(((t - d) & 31) << 8) + tid];
            ar += xv * gfs[d];
            ai += xv * gfs[32 + d];
        }
        x3[base + t * 1024] = __float2bfloat16(sqrtf(ar * ar + ai * ai));
    }
}

// ---------------------------------------------------------------------------
// K2c: temporal depthwise convs (3,1,1) pad1 / (5,1,1) pad2, in-place a1/a2,
// FUSED with BN stat accumulation (sum, sumsq per channel -> atomicAdd).
// 512 blocks x 256 thr; one T-column per thread; each block = single channel.
// ---------------------------------------------------------------------------
__global__ __launch_bounds__(256) void k2c_temporal(float* __restrict__ a1,
                                                    float* __restrict__ a2,
                                                    const float* __restrict__ k32w,
                                                    const float* __restrict__ k32b,
                                                    const float* __restrict__ k52w,
                                                    const float* __restrict__ k52b,
                                                    float* __restrict__ stat) {
    __shared__ float r0[256], r1[256], r2[256], r3[256];
    const int tid = threadIdx.x;
    const int cid = blockIdx.x * 256 + tid;
    const int bc = cid >> 10;
    const int l = cid & 1023;
    const int c = bc & 63;
    const int base = bc * 32768 + l;

    float s1 = 0.f, q1 = 0.f, s2 = 0.f, q2 = 0.f;
    float a[32];
#pragma unroll
    for (int t = 0; t < 32; t++) a[t] = a1[base + t * 1024];
    {
        float w0 = k32w[c * 3], w1 = k32w[c * 3 + 1], w2 = k32w[c * 3 + 2];
        float bb = k32b[c];
#pragma unroll
        for (int t = 0; t < 32; t++) {
            float v = bb + a[t] * w1;
            if (t > 0)  v += a[t - 1] * w0;
            if (t < 31) v += a[t + 1] * w2;
            a1[base + t * 1024] = v;
            s1 += v; q1 += v * v;
        }
    }
#pragma unroll
    for (int t = 0; t < 32; t++) a[t] = a2[base + t * 1024];
    {
        float u0 = k52w[c * 5], u1 = k52w[c * 5 + 1], u2 = k52w[c * 5 + 2];
        float u3 = k52w[c * 5 + 3], u4 = k52w[c * 5 + 4];
        float bb = k52b[c];
#pragma unroll
        for (int t = 0; t < 32; t++) {
            float v = bb + a[t] * u2;
            if (t > 1)  v += a[t - 2] * u0;
            if (t > 0)  v += a[t - 1] * u1;
            if (t < 31) v += a[t + 1] * u3;
            if (t < 30) v += a[t + 2] * u4;
            a2[base + t * 1024] = v;
            s2 += v; q2 += v * v;
        }
    }
    // block reduce (all threads share channel c) + 4 atomics per block
    r0[tid] = s1; r1[tid] = q1; r2[tid] = s2; r3[tid] = q2;
    __syncthreads();
    for (int s = 128; s > 0; s >>= 1) {
        if (tid < s) {
            r0[tid] += r0[tid + s];
            r1[tid] += r1[tid + s];
            r2[tid] += r2[tid + s];
            r3[tid] += r3[tid + s];
        }
        __syncthreads();
    }
    if (tid == 0) {
        atomicAdd(&stat[c],       r0[0]);
        atomicAdd(&stat[64 + c],  r1[0]);
        atomicAdd(&stat[128 + c], r2[0]);
        atomicAdd(&stat[192 + c], r3[0]);
    }
}

// ---------------------------------------------------------------------------
// K2d: BN finalize from accumulated stats. 1 block x 64 thr.
// ---------------------------------------------------------------------------
__global__ __launch_bounds__(64) void k2d_bn(const float* __restrict__ stat,
                                             const float* __restrict__ g3,
                                             const float* __restrict__ b3,
                                             const float* __restrict__ g5,
                                             const float* __restrict__ b5,
                                             float* __restrict__ bnp) {
    const int c = threadIdx.x;
    const float inv_n = 1.0f / 65536.0f;
    float m1 = stat[c] * inv_n;
    float v1 = stat[64 + c] * inv_n - m1 * m1;
    float sc1 = g3[c] * rsqrtf(v1 + 1e-5f);
    float m2 = stat[128 + c] * inv_n;
    float v2 = stat[192 + c] * inv_n - m2 * m2;
    float sc2 = g5[c] * rsqrtf(v2 + 1e-5f);
    bnp[c] = sc1;
    bnp[64 + c] = b3[c] - m1 * sc1;
    bnp[128 + c] = sc2;
    bnp[192 + c] = b5[c] - m2 * sc2;
}

// ---------------------------------------------------------------------------
// K4: s = relu(bn(a1)) + relu(bn(a2)) + x3; attn = cw@s + cb; h5 += attn.
// 512 blocks x 256 thr; 128 positions x 64 ch per block.
// ---------------------------------------------------------------------------
__global__ __launch_bounds__(256) void k4_pointwise(float* __restrict__ h5,
                                                    const float* __restrict__ a1,
                                                    const float* __restrict__ a2,
                                                    const __hip_bfloat16* __restrict__ x3,
                                                    const float* __restrict__ cw,
                                                    const float* __restrict__ cb,
                                                    const float* __restrict__ bnp) {
    __shared__ float ls[64 * 129];
    __shared__ float cs[64 * 64];
    __shared__ float cbs[64];
    __shared__ float bns[256];
    const int tid = threadIdx.x;
    const int pos0 = blockIdx.x * 128;
    const int b = pos0 >> 15;
    const int rem = pos0 & 32767;
    const int t = rem >> 10;
    const int l0 = rem & 1023;
    const int pbase = b * 2097152 + t * 1024 + l0;

#pragma unroll
    for (int i = 0; i < 16; i++) cs[tid + i * 256] = cw[tid + i * 256];
    if (tid < 64) cbs[tid] = cb[tid];
    bns[tid] = bnp[tid];
    __syncthreads();

#pragma unroll
    for (int i = 0; i < 32; i++) {
        int q = tid + i * 256;
        int c = q >> 7, l = q & 127;
        int idx = pbase + c * 32768 + l;
        float v1 = fmaxf(bns[c] * a1[idx] + bns[64 + c], 0.f);
        float v2 = fmaxf(bns[128 + c] * a2[idx] + bns[192 + c], 0.f);
        ls[c * 129 + l] = v1 + v2 + __bfloat162float(x3[idx]);
    }
    __syncthreads();

    const int lidx = tid & 127;
    const int og = tid >> 7;
    float sreg[64];
#pragma unroll
    for (int c = 0; c < 64; c++) sreg[c] = ls[c * 129 + lidx];
    float acc[32];
#pragma unroll
    for (int oi = 0; oi < 32; oi++) acc[oi] = cbs[og * 32 + oi];
#pragma unroll
    for (int cq = 0; cq < 16; cq++) {
        float s0 = sreg[cq * 4], s1 = sreg[cq * 4 + 1];
        float s2 = sreg[cq * 4 + 2], s3 = sreg[cq * 4 + 3];
#pragma unroll
        for (int oi = 0; oi < 32; oi++) {
            float4 wv = *(const float4*)(cs + (og * 32 + oi) * 64 + cq * 4);
            acc[oi] += wv.x * s0 + wv.y * s1 + wv.z * s2 + wv.w * s3;
        }
    }
#pragma unroll
    for (int oi = 0; oi < 32; oi++) {
        int o = og * 32 + oi;
        int idx = pbase + o * 32768 + lidx;
        h5[idx] = h5[idx] + acc[oi];
    }
}

// ---------------------------------------------------------------------------
// K5: up GEMM + bias + GELU + residual -> FLOAT32 out.
// grid (3, 1024) x 256 thr; 64 rows x 128 cols per block; 8 rows x 4 cols
// per thread.
// ---------------------------------------------------------------------------
__global__ __launch_bounds__(256) void k5_up(const float* __restrict__ y5,
                                             const float* __restrict__ uw,
                                             const float* __restrict__ ub,
                                             const float* __restrict__ x,
                                             float* __restrict__ out) {
    __shared__ float ys_t[64 * 68];   // [row][k]
    __shared__ float wts[128 * 68];   // [c][k]
    const int tid = threadIdx.x;
    const int row0 = blockIdx.y * 64;
    const int c0 = blockIdx.x * 128;
    const int b = row0 >> 15;
    const int t = (row0 >> 10) & 31;
    const int l0 = row0 & 1023;
    const int ybase = b * 2097152 + t * 1024 + l0;

    // stage ys_t: 64 k x 64 r, global coalesced along r, LDS write stride 68
#pragma unroll
    for (int i = 0; i < 16; i++) {
        int e = tid + i * 256;
        int k = e >> 6, r = e & 63;
        ys_t[r * 68 + k] = y5[ybase + k * 32768 + r];
    }
    // stage wts: 128 c x 64 k, float4 both sides
#pragma unroll
    for (int i = 0; i < 8; i++) {
        int e = tid + i * 256;
        int c = e >> 4, k4 = e & 15;
        float4 v = *(const float4*)(uw + (c0 + c) * 64 + k4 * 4);
        *(float4*)(wts + c * 68 + k4 * 4) = v;
    }
    __syncthreads();

    const int cg = tid & 31;   // col lane: c = c0 + cg + 32*ci
    const int rg = tid >> 5;   // 0..7:     row = row0 + rg + 8*j
    float acc[8][4];
#pragma unroll
    for (int j = 0; j < 8; j++)
#pragma unroll
        for (int ci = 0; ci < 4; ci++) acc[j][ci] = 0.f;

#pragma unroll 2
    for (int kq = 0; kq < 16; kq++) {
        const int ko = kq * 4;
        float4 w0 = *(const float4*)(wts + (cg)      * 68 + ko);
        float4 w1 = *(const float4*)(wts + (cg + 32) * 68 + ko);
        float4 w2 = *(const float4*)(wts + (cg + 64) * 68 + ko);
        float4 w3 = *(const float4*)(wts + (cg + 96) * 68 + ko);
#pragma unroll
        for (int j = 0; j < 8; j++) {
            float4 yv = *(const float4*)(ys_t + (rg + 8 * j) * 68 + ko);
            acc[j][0] += yv.x * w0.x + yv.y * w0.y + yv.z * w0.z + yv.w * w0.w;
            acc[j][1] += yv.x * w1.x + yv.y * w1.y + yv.z * w1.z + yv.w * w1.w;
            acc[j][2] += yv.x * w2.x + yv.y * w2.y + yv.z * w2.z + yv.w * w2.w;
            acc[j][3] += yv.x * w3.x + yv.y * w3.y + yv.z * w3.z + yv.w * w3.w;
        }
    }

#pragma unroll
    for (int ci = 0; ci < 4; ci++) {
        int c = c0 + cg + 32 * ci;
        float ubv = ub[c];
#pragma unroll
        for (int j = 0; j < 8; j++) {
            int row = row0 + rg + 8 * j;
            float v = gelu_f(acc[j][ci] + ubv);
            out[row * 384 + c] = x[row * 384 + c] + v;
        }
    }
}

// ---------------------------------------------------------------------------
extern "C" void kernel_launch(void* const* d_in, const int* in_sizes, int n_in,
                              void* d_out, int out_size, void* d_ws, size_t ws_size,
                              hipStream_t stream) {
    const float* x      = (const float*)d_in[0];
    const float* down_w = (const float*)d_in[1];
    const float* down_b = (const float*)d_in[2];
    const float* k31w   = (const float*)d_in[3];
    const float* k31b   = (const float*)d_in[4];
    const float* k32w   = (const float*)d_in[5];
    const float* k32b   = (const float*)d_in[6];
    const float* bn3g   = (const float*)d_in[7];
    const float* bn3b   = (const float*)d_in[8];
    const float* k51w   = (const float*)d_in[9];
    const float* k51b   = (const float*)d_in[10];
    const float* k52w   = (const float*)d_in[11];
    const float* k52b   = (const float*)d_in[12];
    const float* bn5g   = (const float*)d_in[13];
    const float* bn5b   = (const float*)d_in[14];
    const float* conv_w = (const float*)d_in[15];
    const float* conv_b = (const float*)d_in[16];
    const float* fw     = (const float*)d_in[17];
    const float* fb     = (const float*)d_in[18];
    const float* up_w   = (const float*)d_in[19];
    const float* up_b   = (const float*)d_in[20];
    float* out = (float*)d_out;

    float* wsf = (float*)d_ws;
    float* gfb  = wsf + OFF_GF;
    float* bnp  = wsf + OFF_BN;
    float* stat = wsf + OFF_ST;
    float* h5   = wsf + OFF_H5;
    float* a1   = wsf + OFF_A1;
    float* a2   = wsf + OFF_A2;
    __hip_bfloat16* x3 = (__hip_bfloat16*)(wsf + OFF_X3);

    k0_prep<<<1, 64, 0, stream>>>(fw, fb, gfb, stat);
    k1_down<<<512, 256, 0, stream>>>(x, down_w, down_b, h5);
    k2a_spatial<<<4096, 256, 0, stream>>>(h5, k31w, k31b, k51w, k51b, a1, a2);
    k2b_fft<<<512, 256, 0, stream>>>(h5, x3, gfb);
    k2c_temporal<<<512, 256, 0, stream>>>(a1, a2, k32w, k32b, k52w, k52b, stat);
    k2d_bn<<<1, 64, 0, stream>>>(stat, bn3g, bn3b, bn5g, bn5b, bnp);
    k4_pointwise<<<512, 256, 0, stream>>>(h5, a1, a2, x3, conv_w, conv_b, bnp);
    k5_up<<<dim3(3, 1024), 256, 0, stream>>>(h5, up_w, up_b, x, out);
}

// Round 6
// 546.744 us; speedup vs baseline: 1.7576x; 1.7576x over previous
//
#include <hip/hip_runtime.h>
#include <hip/hip_bf16.h>
#include <math.h>

// B=2, T=32, H=32, W=32, HID=64, IN=384, OUT=384, L=1024, rows=65536
// h5 layout: [b][c][t][l] -> b*2097152 + c*32768 + t*1024 + l
// OUTPUT IS FLOAT32 (reference returns fp32).
// ws layout (float offsets): gf[128] @0, bnp[256] @128, stat[256] @384,
// h5 @1024, a1 @4195328, a2 @8389632, x3(bf16) @12583936. total = 58.7 MB
// R11: k1 redesigned as scalar-W GEMM. History of the fp32 LDS-GEMM wall:
//  R1/(256,4) & R5/(256,2)+8x4: VGPR cap < working set -> scratch spill
//  (2+ GB HBM, VALU <7%). R3/(256,1): VGPR=256, 1-2 waves/SIMD, 201us.
//  R4 4x4: 128us, LDS-issue-bound (VALU duty 33% == predicted 128/384).
//  Lesson: per-lane LDS reads for BOTH operands caps this at ~128us.
//  R11: wave owns 16 channels -> W fragment is WAVE-UNIFORM -> s_load
//  (scalar cache, no LDS/VMEM issue); lane owns a row -> 1 ds_read_b128
//  per kq; epilogue planar store naturally coalesced (lane=row), no
//  LDS transpose. ~45 VGPR, LDS 18KB, 4 waves/SIMD.
// k2c fused BN stats (atomicAdd, zeroed in k0); k2d = 1-block finalize.

#define OFF_GF 0
#define OFF_BN 128
#define OFF_ST 384
#define OFF_H5 1024
#define OFF_A1 4195328
#define OFF_A2 8389632
#define OFF_X3 12583936

__device__ __forceinline__ float gelu_f(float v) {
    return 0.5f * v * (1.0f + erff(v * 0.70710678118654752f));
}

// ---------------------------------------------------------------------------
// K0: g = ifft_T(fw), F = ifft_T(fb) (T=32). gf: gr[32] gi[32] Fr[32] Fi[32]
// Also zeroes the BN-stat accumulators (re-zeroed on every graph replay).
// ---------------------------------------------------------------------------
__global__ __launch_bounds__(64) void k0_prep(const float* __restrict__ fw,
                                              const float* __restrict__ fb,
                                              float* __restrict__ gf,
                                              float* __restrict__ stat) {
    int tid = threadIdx.x;
    stat[tid] = 0.f;
    stat[64 + tid] = 0.f;
    stat[128 + tid] = 0.f;
    stat[192 + tid] = 0.f;
    if (tid < 32) {
        float gr = 0.f, gi = 0.f, Fr = 0.f, Fi = 0.f;
        for (int f = 0; f < 32; f++) {
            int ph = (f * tid) & 31;
            float ang = 6.283185307179586f * (float)ph * (1.0f / 32.0f);
            float s, c;
            __sincosf(ang, &s, &c);
            float wv = fw[f], bv = fb[f];
            gr += wv * c; gi += wv * s;
            Fr += bv * c; Fi += bv * s;
        }
        const float inv = 1.0f / 32.0f;
        gf[tid]      = gr * inv;
        gf[32 + tid] = gi * inv;
        gf[64 + tid] = Fr * inv;
        gf[96 + tid] = Fi * inv;
    }
}

// ---------------------------------------------------------------------------
// K1: down GEMM + bias + GELU -> h5 (channel-planar), scalar-W design.
// 1024 blocks x 256 thr (4 waves). Block: 64 rows x 64 ch; wave w handles
// ch [16w,16w+16) x all 64 rows; lane = row. Per kq: ONE ds_read_b128 (x
// row fragment) + 16 wave-uniform W float4 loads (s_load_dwordx4, scalar
// cache) + 64 v_fma (SGPR operand). x double-buffered in LDS (stride 36:
// lane banks 4l%32 -> conflict-free), one barrier per K-step, loads 2
// steps ahead. Epilogue: lane=row => planar h5 stores are 64x4B coalesced.
// ---------------------------------------------------------------------------
__global__ __launch_bounds__(256, 2) void k1_down(const float* __restrict__ x,
                                                  const float* __restrict__ dw,
                                                  const float* __restrict__ db,
                                                  float* __restrict__ h5) {
    __shared__ __align__(16) float xs[2 * 2304];   // 2 x (64 rows x 36)
    const int tid = threadIdx.x;
    const int lane = tid & 63;
    const int c0 = __builtin_amdgcn_readfirstlane((tid >> 6) * 16);
    const int row0 = blockIdx.x * 64;

    // staging coords: rows sr, sr+32 at k-quad sk (coalesced float4)
    const int sr = tid >> 3;        // 0..31
    const int sk = (tid & 7) * 4;   // 0,4,...,28
    const float* xp = x + (row0 + sr) * 384 + sk;

    float acc[16];
#pragma unroll
    for (int i = 0; i < 16; i++) acc[i] = 0.f;

    // prologue: tile 0 -> buf0, issue tile 1 loads
    float4 r0 = *(const float4*)(xp);
    float4 r1 = *(const float4*)(xp + 32 * 384);
    *(float4*)(xs + sr * 36 + sk) = r0;
    *(float4*)(xs + (sr + 32) * 36 + sk) = r1;
    r0 = *(const float4*)(xp + 32);
    r1 = *(const float4*)(xp + 32 + 32 * 384);
    __syncthreads();

    for (int s = 0; s < 12; s++) {
        float* cb = xs + (s & 1) * 2304;         // compute buffer
        float* nb = xs + ((s + 1) & 1) * 2304;   // next buffer
        if (s < 11) {
            // tile s+1 regs -> nb (vmcnt wait lands here); nb's readers
            // (tile s-1 compute) finished before the last barrier.
            *(float4*)(nb + sr * 36 + sk) = r0;
            *(float4*)(nb + (sr + 32) * 36 + sk) = r1;
            if (s < 10) {
                const int kc = (s + 2) * 32;
                r0 = *(const float4*)(xp + kc);
                r1 = *(const float4*)(xp + kc + 32 * 384);
            }
        }
        const int kcc = s * 32;
#pragma unroll
        for (int kq = 0; kq < 8; kq++) {
            float4 xv = *(const float4*)(cb + lane * 36 + kq * 4);
            const float* wq = dw + c0 * 384 + kcc + kq * 4;   // wave-uniform
#pragma unroll
            for (int cc = 0; cc < 16; cc++) {
                float4 wv = *(const float4*)(wq + cc * 384);  // s_load_dwordx4
                acc[cc] += xv.x * wv.x + xv.y * wv.y +
                           xv.z * wv.z + xv.w * wv.w;
            }
        }
        __syncthreads();
    }

    // epilogue: planar stores, lane=row -> fully coalesced, no transpose
    const int b = row0 >> 15;
    const int t = (row0 >> 10) & 31;
    const int l0 = row0 & 1023;
    float* hbase = h5 + b * 2097152 + t * 1024 + l0 + lane;
#pragma unroll
    for (int cc = 0; cc < 16; cc++) {
        const int c = c0 + cc;
        hbase[c * 32768] = gelu_f(acc[cc] + db[c]);
    }
}

// ---------------------------------------------------------------------------
// K2a: spatial depthwise (1,3,3) pad1 & (1,5,5) pad2 per (b,c,t) plane.
// 4096 blocks x 256 thr.
// ---------------------------------------------------------------------------
__global__ __launch_bounds__(256) void k2a_spatial(const float* __restrict__ h5,
                                                   const float* __restrict__ k31w,
                                                   const float* __restrict__ k31b,
                                                   const float* __restrict__ k51w,
                                                   const float* __restrict__ k51b,
                                                   float* __restrict__ a1,
                                                   float* __restrict__ a2) {
    __shared__ float pl[32 * 33];
    __shared__ float w3[9];
    __shared__ float w5[25];
    const int tid = threadIdx.x;
    const int bct = blockIdx.x;
    const int base = bct << 10;
    const int c = (bct >> 5) & 63;

#pragma unroll
    for (int i = 0; i < 4; i++) {
        int l = tid + i * 256;
        pl[(l >> 5) * 33 + (l & 31)] = h5[base + l];
    }
    if (tid < 9)  w3[tid] = k31w[c * 9 + tid];
    if (tid < 25) w5[tid] = k51w[c * 25 + tid];
    float b3 = k31b[c], b5 = k51b[c];
    __syncthreads();

#pragma unroll
    for (int i = 0; i < 4; i++) {
        int l = tid + i * 256;
        int h = l >> 5, w = l & 31;
        float s3 = b3;
#pragma unroll
        for (int dh = -1; dh <= 1; dh++) {
            int hh = h + dh;
            if (hh < 0 || hh > 31) continue;
#pragma unroll
            for (int dwi = -1; dwi <= 1; dwi++) {
                int ww = w + dwi;
                if (ww < 0 || ww > 31) continue;
                s3 += pl[hh * 33 + ww] * w3[(dh + 1) * 3 + dwi + 1];
            }
        }
        float s5 = b5;
#pragma unroll
        for (int dh = -2; dh <= 2; dh++) {
            int hh = h + dh;
            if (hh < 0 || hh > 31) continue;
#pragma unroll
            for (int dwi = -2; dwi <= 2; dwi++) {
                int ww = w + dwi;
                if (ww < 0 || ww > 31) continue;
                s5 += pl[hh * 33 + ww] * w5[(dh + 2) * 5 + dwi + 2];
            }
        }
        a1[base + l] = s3;
        a2[base + l] = s5;
    }
}

// ---------------------------------------------------------------------------
// K2b: FFT branch = complex circular conv along T (+ ifft(fb) delta at l==0),
// magnitude -> x3 (bf16). 512 blocks x 256 thr.
// ---------------------------------------------------------------------------
__global__ __launch_bounds__(256) void k2b_fft(const float* __restrict__ h5,
                                               __hip_bfloat16* __restrict__ x3,
                                               const float* __restrict__ gf) {
    __shared__ float col[32 * 256];
    __shared__ float gfs[128];
    const int tid = threadIdx.x;
    const int bid = blockIdx.x;
    const int bc = bid >> 2;
    const int l = (bid & 3) * 256 + tid;
    const int base = bc * 32768 + l;

    if (tid < 128) gfs[tid] = gf[tid];
#pragma unroll
    for (int t = 0; t < 32; t++) col[t * 256 + tid] = h5[base + t * 1024];
    __syncthreads();

    const bool dc = (l == 0);
    for (int t = 0; t < 32; t++) {
        float ar = dc ? gfs[64 + t] : 0.f;
        float ai = dc ? gfs[96 + t] : 0.f;
#pragma unroll
        for (int d = 0; d < 32; d++) {
            float xv = col[(((t - d) & 31) << 8) + tid];
            ar += xv * gfs[d];
            ai += xv * gfs[32 + d];
        }
        x3[base + t * 1024] = __float2bfloat16(sqrtf(ar * ar + ai * ai));
    }
}

// ---------------------------------------------------------------------------
// K2c: temporal depthwise convs (3,1,1) pad1 / (5,1,1) pad2, in-place a1/a2,
// FUSED with BN stat accumulation (sum, sumsq per channel -> atomicAdd).
// 512 blocks x 256 thr; one T-column per thread; each block = single channel.
// ---------------------------------------------------------------------------
__global__ __launch_bounds__(256) void k2c_temporal(float* __restrict__ a1,
                                                    float* __restrict__ a2,
                                                    const float* __restrict__ k32w,
                                                    const float* __restrict__ k32b,
                                                    const float* __restrict__ k52w,
                                                    const float* __restrict__ k52b,
                                                    float* __restrict__ stat) {
    __shared__ float r0[256], r1[256], r2[256], r3[256];
    const int tid = threadIdx.x;
    const int cid = blockIdx.x * 256 + tid;
    const int bc = cid >> 10;
    const int l = cid & 1023;
    const int c = bc & 63;
    const int base = bc * 32768 + l;

    float s1 = 0.f, q1 = 0.f, s2 = 0.f, q2 = 0.f;
    float a[32];
#pragma unroll
    for (int t = 0; t < 32; t++) a[t] = a1[base + t * 1024];
    {
        float w0 = k32w[c * 3], w1 = k32w[c * 3 + 1], w2 = k32w[c * 3 + 2];
        float bb = k32b[c];
#pragma unroll
        for (int t = 0; t < 32; t++) {
            float v = bb + a[t] * w1;
            if (t > 0)  v += a[t - 1] * w0;
            if (t < 31) v += a[t + 1] * w2;
            a1[base + t * 1024] = v;
            s1 += v; q1 += v * v;
        }
    }
#pragma unroll
    for (int t = 0; t < 32; t++) a[t] = a2[base + t * 1024];
    {
        float u0 = k52w[c * 5], u1 = k52w[c * 5 + 1], u2 = k52w[c * 5 + 2];
        float u3 = k52w[c * 5 + 3], u4 = k52w[c * 5 + 4];
        float bb = k52b[c];
#pragma unroll
        for (int t = 0; t < 32; t++) {
            float v = bb + a[t] * u2;
            if (t > 1)  v += a[t - 2] * u0;
            if (t > 0)  v += a[t - 1] * u1;
            if (t < 31) v += a[t + 1] * u3;
            if (t < 30) v += a[t + 2] * u4;
            a2[base + t * 1024] = v;
            s2 += v; q2 += v * v;
        }
    }
    // block reduce (all threads share channel c) + 4 atomics per block
    r0[tid] = s1; r1[tid] = q1; r2[tid] = s2; r3[tid] = q2;
    __syncthreads();
    for (int s = 128; s > 0; s >>= 1) {
        if (tid < s) {
            r0[tid] += r0[tid + s];
            r1[tid] += r1[tid + s];
            r2[tid] += r2[tid + s];
            r3[tid] += r3[tid + s];
        }
        __syncthreads();
    }
    if (tid == 0) {
        atomicAdd(&stat[c],       r0[0]);
        atomicAdd(&stat[64 + c],  r1[0]);
        atomicAdd(&stat[128 + c], r2[0]);
        atomicAdd(&stat[192 + c], r3[0]);
    }
}

// ---------------------------------------------------------------------------
// K2d: BN finalize from accumulated stats. 1 block x 64 thr.
// ---------------------------------------------------------------------------
__global__ __launch_bounds__(64) void k2d_bn(const float* __restrict__ stat,
                                             const float* __restrict__ g3,
                                             const float* __restrict__ b3,
                                             const float* __restrict__ g5,
                                             const float* __restrict__ b5,
                                             float* __restrict__ bnp) {
    const int c = threadIdx.x;
    const float inv_n = 1.0f / 65536.0f;
    float m1 = stat[c] * inv_n;
    float v1 = stat[64 + c] * inv_n - m1 * m1;
    float sc1 = g3[c] * rsqrtf(v1 + 1e-5f);
    float m2 = stat[128 + c] * inv_n;
    float v2 = stat[192 + c] * inv_n - m2 * m2;
    float sc2 = g5[c] * rsqrtf(v2 + 1e-5f);
    bnp[c] = sc1;
    bnp[64 + c] = b3[c] - m1 * sc1;
    bnp[128 + c] = sc2;
    bnp[192 + c] = b5[c] - m2 * sc2;
}

// ---------------------------------------------------------------------------
// K4: s = relu(bn(a1)) + relu(bn(a2)) + x3; attn = cw@s + cb; h5 += attn.
// 512 blocks x 256 thr; 128 positions x 64 ch per block.
// ---------------------------------------------------------------------------
__global__ __launch_bounds__(256) void k4_pointwise(float* __restrict__ h5,
                                                    const float* __restrict__ a1,
                                                    const float* __restrict__ a2,
                                                    const __hip_bfloat16* __restrict__ x3,
                                                    const float* __restrict__ cw,
                                                    const float* __restrict__ cb,
                                                    const float* __restrict__ bnp) {
    __shared__ float ls[64 * 129];
    __shared__ float cs[64 * 64];
    __shared__ float cbs[64];
    __shared__ float bns[256];
    const int tid = threadIdx.x;
    const int pos0 = blockIdx.x * 128;
    const int b = pos0 >> 15;
    const int rem = pos0 & 32767;
    const int t = rem >> 10;
    const int l0 = rem & 1023;
    const int pbase = b * 2097152 + t * 1024 + l0;

#pragma unroll
    for (int i = 0; i < 16; i++) cs[tid + i * 256] = cw[tid + i * 256];
    if (tid < 64) cbs[tid] = cb[tid];
    bns[tid] = bnp[tid];
    __syncthreads();

#pragma unroll
    for (int i = 0; i < 32; i++) {
        int q = tid + i * 256;
        int c = q >> 7, l = q & 127;
        int idx = pbase + c * 32768 + l;
        float v1 = fmaxf(bns[c] * a1[idx] + bns[64 + c], 0.f);
        float v2 = fmaxf(bns[128 + c] * a2[idx] + bns[192 + c], 0.f);
        ls[c * 129 + l] = v1 + v2 + __bfloat162float(x3[idx]);
    }
    __syncthreads();

    const int lidx = tid & 127;
    const int og = tid >> 7;
    float sreg[64];
#pragma unroll
    for (int c = 0; c < 64; c++) sreg[c] = ls[c * 129 + lidx];
    float acc[32];
#pragma unroll
    for (int oi = 0; oi < 32; oi++) acc[oi] = cbs[og * 32 + oi];
#pragma unroll
    for (int cq = 0; cq < 16; cq++) {
        float s0 = sreg[cq * 4], s1 = sreg[cq * 4 + 1];
        float s2 = sreg[cq * 4 + 2], s3 = sreg[cq * 4 + 3];
#pragma unroll
        for (int oi = 0; oi < 32; oi++) {
            float4 wv = *(const float4*)(cs + (og * 32 + oi) * 64 + cq * 4);
            acc[oi] += wv.x * s0 + wv.y * s1 + wv.z * s2 + wv.w * s3;
        }
    }
#pragma unroll
    for (int oi = 0; oi < 32; oi++) {
        int o = og * 32 + oi;
        int idx = pbase + o * 32768 + lidx;
        h5[idx] = h5[idx] + acc[oi];
    }
}

// ---------------------------------------------------------------------------
// K5: up GEMM + bias + GELU + residual -> FLOAT32 out.
// grid (3, 1024) x 256 thr; 64 rows x 128 cols per block; 8 rows x 4 cols
// per thread.
// ---------------------------------------------------------------------------
__global__ __launch_bounds__(256) void k5_up(const float* __restrict__ y5,
                                             const float* __restrict__ uw,
                                             const float* __restrict__ ub,
                                             const float* __restrict__ x,
                                             float* __restrict__ out) {
    __shared__ float ys_t[64 * 68];   // [row][k]
    __shared__ float wts[128 * 68];   // [c][k]
    const int tid = threadIdx.x;
    const int row0 = blockIdx.y * 64;
    const int c0 = blockIdx.x * 128;
    const int b = row0 >> 15;
    const int t = (row0 >> 10) & 31;
    const int l0 = row0 & 1023;
    const int ybase = b * 2097152 + t * 1024 + l0;

    // stage ys_t: 64 k x 64 r, global coalesced along r, LDS write stride 68
#pragma unroll
    for (int i = 0; i < 16; i++) {
        int e = tid + i * 256;
        int k = e >> 6, r = e & 63;
        ys_t[r * 68 + k] = y5[ybase + k * 32768 + r];
    }
    // stage wts: 128 c x 64 k, float4 both sides
#pragma unroll
    for (int i = 0; i < 8; i++) {
        int e = tid + i * 256;
        int c = e >> 4, k4 = e & 15;
        float4 v = *(const float4*)(uw + (c0 + c) * 64 + k4 * 4);
        *(float4*)(wts + c * 68 + k4 * 4) = v;
    }
    __syncthreads();

    const int cg = tid & 31;   // col lane: c = c0 + cg + 32*ci
    const int rg = tid >> 5;   // 0..7:     row = row0 + rg + 8*j
    float acc[8][4];
#pragma unroll
    for (int j = 0; j < 8; j++)
#pragma unroll
        for (int ci = 0; ci < 4; ci++) acc[j][ci] = 0.f;

#pragma unroll 2
    for (int kq = 0; kq < 16; kq++) {
        const int ko = kq * 4;
        float4 w0 = *(const float4*)(wts + (cg)      * 68 + ko);
        float4 w1 = *(const float4*)(wts + (cg + 32) * 68 + ko);
        float4 w2 = *(const float4*)(wts + (cg + 64) * 68 + ko);
        float4 w3 = *(const float4*)(wts + (cg + 96) * 68 + ko);
#pragma unroll
        for (int j = 0; j < 8; j++) {
            float4 yv = *(const float4*)(ys_t + (rg + 8 * j) * 68 + ko);
            acc[j][0] += yv.x * w0.x + yv.y * w0.y + yv.z * w0.z + yv.w * w0.w;
            acc[j][1] += yv.x * w1.x + yv.y * w1.y + yv.z * w1.z + yv.w * w1.w;
            acc[j][2] += yv.x * w2.x + yv.y * w2.y + yv.z * w2.z + yv.w * w2.w;
            acc[j][3] += yv.x * w3.x + yv.y * w3.y + yv.z * w3.z + yv.w * w3.w;
        }
    }

#pragma unroll
    for (int ci = 0; ci < 4; ci++) {
        int c = c0 + cg + 32 * ci;
        float ubv = ub[c];
#pragma unroll
        for (int j = 0; j < 8; j++) {
            int row = row0 + rg + 8 * j;
            float v = gelu_f(acc[j][ci] + ubv);
            out[row * 384 + c] = x[row * 384 + c] + v;
        }
    }
}

// ---------------------------------------------------------------------------
extern "C" void kernel_launch(void* const* d_in, const int* in_sizes, int n_in,
                              void* d_out, int out_size, void* d_ws, size_t ws_size,
                              hipStream_t stream) {
    const float* x      = (const float*)d_in[0];
    const float* down_w = (const float*)d_in[1];
    const float* down_b = (const float*)d_in[2];
    const float* k31w   = (const float*)d_in[3];
    const float* k31b   = (const float*)d_in[4];
    const float* k32w   = (const float*)d_in[5];
    const float* k32b   = (const float*)d_in[6];
    const float* bn3g   = (const float*)d_in[7];
    const float* bn3b   = (const float*)d_in[8];
    const float* k51w   = (const float*)d_in[9];
    const float* k51b   = (const float*)d_in[10];
    const float* k52w   = (const float*)d_in[11];
    const float* k52b   = (const float*)d_in[12];
    const float* bn5g   = (const float*)d_in[13];
    const float* bn5b   = (const float*)d_in[14];
    const float* conv_w = (const float*)d_in[15];
    const float* conv_b = (const float*)d_in[16];
    const float* fw     = (const float*)d_in[17];
    const float* fb     = (const float*)d_in[18];
    const float* up_w   = (const float*)d_in[19];
    const float* up_b   = (const float*)d_in[20];
    float* out = (float*)d_out;

    float* wsf = (float*)d_ws;
    float* gfb  = wsf + OFF_GF;
    float* bnp  = wsf + OFF_BN;
    float* stat = wsf + OFF_ST;
    float* h5   = wsf + OFF_H5;
    float* a1   = wsf + OFF_A1;
    float* a2   = wsf + OFF_A2;
    __hip_bfloat16* x3 = (__hip_bfloat16*)(wsf + OFF_X3);

    k0_prep<<<1, 64, 0, stream>>>(fw, fb, gfb, stat);
    k1_down<<<1024, 256, 0, stream>>>(x, down_w, down_b, h5);
    k2a_spatial<<<4096, 256, 0, stream>>>(h5, k31w, k31b, k51w, k51b, a1, a2);
    k2b_fft<<<512, 256, 0, stream>>>(h5, x3, gfb);
    k2c_temporal<<<512, 256, 0, stream>>>(a1, a2, k32w, k32b, k52w, k52b, stat);
    k2d_bn<<<1, 64, 0, stream>>>(stat, bn3g, bn3b, bn5g, bn5b, bnp);
    k4_pointwise<<<512, 256, 0, stream>>>(h5, a1, a2, x3, conv_w, conv_b, bnp);
    k5_up<<<dim3(3, 1024), 256, 0, stream>>>(h5, up_w, up_b, x, out);
}